// Round 11
// baseline (382.463 us; speedup 1.0000x reference)
//
#include <hip/hip_runtime.h>
#include <hip/hip_bf16.h>

#define NN 50000
#define EE 1600000
#define DH 128
#define DOUT 64
#define NEG 0.2f
#define NBK 256            // bucket array size (used: (NN+255)>>8 = 196)
#define CHUNK 4096         // edges per scatter block
#define BCAP 10240         // per-bucket pair capacity (lambda=8192, +22 sigma)
#define CCAP 12288         // per-bucket csr capacity (BCAP + 256*8 pad slack)

typedef short bf16x8 __attribute__((ext_vector_type(8)));
typedef float f32x4 __attribute__((ext_vector_type(4)));

// ---------------- CSR build (single-pass bucketed) ----------------

// scatter packed (dstlow<<16 | src) into fixed-capacity bucket regions
__global__ __launch_bounds__(256) void k_scatter(const int* __restrict__ src,
                                                 const int* __restrict__ dst,
                                                 int* __restrict__ bucket_cursor,
                                                 unsigned int* __restrict__ pairs) {
    __shared__ int lh[NBK];
    __shared__ int lbase[NBK];
    lh[threadIdx.x] = 0;
    __syncthreads();
    const int e0 = blockIdx.x * CHUNK;
    int dl[CHUNK / 256];
    #pragma unroll
    for (int k = 0; k < CHUNK / 256; k++) {
        int e = e0 + k * 256 + threadIdx.x;
        dl[k] = (e < EE) ? dst[e] : -1;
        if (dl[k] >= 0) atomicAdd(&lh[((unsigned)dl[k]) >> 8], 1);
    }
    __syncthreads();
    int c = lh[threadIdx.x];
    lbase[threadIdx.x] = c ? (threadIdx.x * BCAP +
                              atomicAdd(&bucket_cursor[threadIdx.x], c)) : 0;
    __syncthreads();
    lh[threadIdx.x] = 0;   // reuse as local running cursor
    __syncthreads();
    #pragma unroll
    for (int k = 0; k < CHUNK / 256; k++) {
        int e = e0 + k * 256 + threadIdx.x;
        if (dl[k] >= 0) {
            int b = ((unsigned)dl[k]) >> 8;
            int loc = atomicAdd(&lh[b], 1);
            pairs[lbase[b] + loc] =
                (unsigned)src[e] | (((unsigned)dl[k] & 255u) << 16);
        }
    }
}

// per-bucket: LDS histogram + padded scan + fill + pad; writes deg/prow/csr.
__global__ __launch_bounds__(256) void k_bucket(const unsigned int* __restrict__ pairs,
                                                const int* __restrict__ bucket_cursor,
                                                int* __restrict__ csr_off,
                                                int* __restrict__ prow,
                                                int* __restrict__ deg) {
    __shared__ int cnt[256];
    __shared__ int sbase[256];
    __shared__ int scn[256];
    __shared__ int cur[256];
    const int b = blockIdx.x;
    const int t = threadIdx.x;
    const int pstart = b * BCAP;
    const int pcnt = bucket_cursor[b];

    cnt[t] = 0;
    cur[t] = 0;
    __syncthreads();
    for (int i = t; i < pcnt; i += 256)
        atomicAdd(&cnt[pairs[pstart + i] >> 16], 1);
    __syncthreads();

    const int d = cnt[t];
    const int padded = (d + 7) & ~7;
    scn[t] = padded;
    __syncthreads();
    #pragma unroll
    for (int off = 1; off < 256; off <<= 1) {
        int v = (t >= off) ? scn[t - off] : 0;
        __syncthreads();
        scn[t] += v;
        __syncthreads();
    }
    const int mybase = scn[t] - padded;   // exclusive scan (bucket-relative)
    sbase[t] = mybase;
    const int cb = b * CCAP;              // csr region base for this bucket
    const int node = b * 256 + t;
    if (node < NN) {
        prow[node] = cb + mybase;
        deg[node] = d;
    }
    __syncthreads();

    for (int i = t; i < pcnt; i += 256) {
        unsigned int pr = pairs[pstart + i];
        int ln = (int)(pr >> 16);
        int pos = atomicAdd(&cur[ln], 1);
        csr_off[cb + sbase[ln] + pos] = (int)((pr & 0xffffu) << 8);
    }
    __syncthreads();

    for (int p = d; p < padded; p++) csr_off[cb + mybase + p] = 0;
}

// ---------------- helpers ----------------

static __device__ __forceinline__ unsigned int f2bf(float f) {
    unsigned int u = __float_as_uint(f);
    return (u + 0x7fffu + ((u >> 16) & 1u)) >> 16;  // RNE
}
static __device__ __forceinline__ unsigned int pack2bf(float lo, float hi) {
    return f2bf(lo) | (f2bf(hi) << 16);
}

// ---------------- merged dual MFMA GEMM ----------------
// One block: stage A once (fp32->bf16 if !ABF, else raw bf16 copy) + both
// W tiles; compute A@Wl.T + bl -> xl16 (packed bf16), then A@Wr.T + br ->
// xrb (fp32). LDS 48KB. 4 waves, wave quadrant 64x64.

template <bool ABF>
__global__ __launch_bounds__(256) void k_dual(const void* __restrict__ X,
                                              const float* __restrict__ Wl,
                                              const float* __restrict__ bl,
                                              unsigned int* __restrict__ Cl,
                                              const float* __restrict__ Wr,
                                              const float* __restrict__ br,
                                              float* __restrict__ Cr,
                                              int nrows) {
    __shared__ __align__(16) unsigned short As[4][4][128][8];
    __shared__ __align__(16) unsigned short Bl[4][4][128][8];
    __shared__ __align__(16) unsigned short Br[4][4][128][8];

    const int tid = threadIdx.x;
    const int row0 = blockIdx.x * 128;

    // stage A
    if constexpr (ABF) {
        const uint4* X4 = (const uint4*)X;
        #pragma unroll
        for (int i = 0; i < 8; i++) {
            int L = i * 256 + tid;          // 2048 uint4 (128 rows x 16)
            int r = L >> 4, q = L & 15;
            int gr = row0 + r;
            uint4 v = make_uint4(0u, 0u, 0u, 0u);
            if (gr < nrows) v = X4[(size_t)gr * 16 + q];
            *(uint4*)&As[q >> 2][q & 3][r][0] = v;
        }
    } else {
        const float* Xf = (const float*)X;
        #pragma unroll
        for (int i = 0; i < 16; i++) {
            int L = i * 256 + tid;          // 4096 float4
            int r = L >> 5, kq = L & 31;
            int gr = row0 + r;
            float4 v = make_float4(0.f, 0.f, 0.f, 0.f);
            if (gr < nrows) v = *(const float4*)&Xf[(size_t)gr * 128 + kq * 4];
            int k = kq * 4;
            *(uint2*)&As[k >> 5][(k >> 3) & 3][r][k & 7] =
                make_uint2(pack2bf(v.x, v.y), pack2bf(v.z, v.w));
        }
    }
    // stage Bl, Br (128x128 fp32 -> bf16 each)
    #pragma unroll
    for (int i = 0; i < 16; i++) {
        int L = i * 256 + tid;
        int r = L >> 5, kq = L & 31;
        int k = kq * 4;
        float4 v = *(const float4*)&Wl[(size_t)r * 128 + kq * 4];
        *(uint2*)&Bl[k >> 5][(k >> 3) & 3][r][k & 7] =
            make_uint2(pack2bf(v.x, v.y), pack2bf(v.z, v.w));
        float4 u = *(const float4*)&Wr[(size_t)r * 128 + kq * 4];
        *(uint2*)&Br[k >> 5][(k >> 3) & 3][r][k & 7] =
            make_uint2(pack2bf(u.x, u.y), pack2bf(u.z, u.w));
    }
    __syncthreads();

    const int w = tid >> 6;
    const int lane = tid & 63;
    const int lr = lane & 15;
    const int kg = lane >> 4;
    const int rowbase = (w >> 1) * 64;
    const int colbase = (w & 1) * 64;

    f32x4 acc[4][4];

    // ---- pass 1: Wl -> packed bf16 ----
    #pragma unroll
    for (int i = 0; i < 4; i++)
        #pragma unroll
        for (int j = 0; j < 4; j++) acc[i][j] = (f32x4){0.f, 0.f, 0.f, 0.f};
    #pragma unroll
    for (int kc = 0; kc < 4; kc++) {
        bf16x8 af[4], bfr[4];
        #pragma unroll
        for (int i = 0; i < 4; i++)
            af[i] = *(const bf16x8*)&As[kc][kg][rowbase + i * 16 + lr][0];
        #pragma unroll
        for (int j = 0; j < 4; j++)
            bfr[j] = *(const bf16x8*)&Bl[kc][kg][colbase + j * 16 + lr][0];
        #pragma unroll
        for (int i = 0; i < 4; i++)
            #pragma unroll
            for (int j = 0; j < 4; j++)
                acc[i][j] = __builtin_amdgcn_mfma_f32_16x16x32_bf16(af[i], bfr[j],
                                                                    acc[i][j], 0, 0, 0);
    }
    #pragma unroll
    for (int i = 0; i < 4; i++) {
        #pragma unroll
        for (int reg = 0; reg < 4; reg++) {
            int row = rowbase + i * 16 + (lane >> 4) * 4 + reg;
            int gr = row0 + row;
            if (gr < nrows) {
                #pragma unroll
                for (int j = 0; j < 4; j++) {
                    int col = colbase + j * 16 + lr;
                    float v = acc[i][j][reg] + bl[col];
                    float vn = __shfl_xor(v, 1, 64);
                    if (!(lane & 1))
                        Cl[(size_t)gr * (DH / 2) + (col >> 1)] = pack2bf(v, vn);
                }
            }
        }
    }

    // ---- pass 2: Wr -> fp32 ----
    #pragma unroll
    for (int i = 0; i < 4; i++)
        #pragma unroll
        for (int j = 0; j < 4; j++) acc[i][j] = (f32x4){0.f, 0.f, 0.f, 0.f};
    #pragma unroll
    for (int kc = 0; kc < 4; kc++) {
        bf16x8 af[4], bfr[4];
        #pragma unroll
        for (int i = 0; i < 4; i++)
            af[i] = *(const bf16x8*)&As[kc][kg][rowbase + i * 16 + lr][0];
        #pragma unroll
        for (int j = 0; j < 4; j++)
            bfr[j] = *(const bf16x8*)&Br[kc][kg][colbase + j * 16 + lr][0];
        #pragma unroll
        for (int i = 0; i < 4; i++)
            #pragma unroll
            for (int j = 0; j < 4; j++)
                acc[i][j] = __builtin_amdgcn_mfma_f32_16x16x32_bf16(af[i], bfr[j],
                                                                    acc[i][j], 0, 0, 0);
    }
    #pragma unroll
    for (int i = 0; i < 4; i++) {
        #pragma unroll
        for (int reg = 0; reg < 4; reg++) {
            int row = rowbase + i * 16 + (lane >> 4) * 4 + reg;
            int gr = row0 + row;
            if (gr < nrows) {
                #pragma unroll
                for (int j = 0; j < 4; j++) {
                    int col = colbase + j * 16 + lr;
                    Cr[(size_t)gr * DH + col] = acc[i][j][reg] + br[col];
                }
            }
        }
    }
}

// ---------------- fused head: out = (X@W1.T + b1)@W2.T + b2 ----------------

__global__ __launch_bounds__(256) void k_head(const void* __restrict__ Xbf,
                                              const float* __restrict__ W1,
                                              const float* __restrict__ b1,
                                              const float* __restrict__ W2,
                                              const float* __restrict__ b2,
                                              float* __restrict__ out,
                                              int nrows) {
    __shared__ __align__(16) unsigned short As[4][4][128][8];
    __shared__ __align__(16) unsigned short Bs[4][4][128][8];

    const int tid = threadIdx.x;
    const int row0 = blockIdx.x * 128;

    const uint4* X4 = (const uint4*)Xbf;
    #pragma unroll
    for (int i = 0; i < 8; i++) {
        int L = i * 256 + tid;
        int r = L >> 4, q = L & 15;
        int gr = row0 + r;
        uint4 v = make_uint4(0u, 0u, 0u, 0u);
        if (gr < nrows) v = X4[(size_t)gr * 16 + q];
        *(uint4*)&As[q >> 2][q & 3][r][0] = v;
    }
    #pragma unroll
    for (int i = 0; i < 16; i++) {
        int L = i * 256 + tid;
        int r = L >> 5, kq = L & 31;
        float4 v = *(const float4*)&W1[(size_t)r * 128 + kq * 4];
        int k = kq * 4;
        *(uint2*)&Bs[k >> 5][(k >> 3) & 3][r][k & 7] =
            make_uint2(pack2bf(v.x, v.y), pack2bf(v.z, v.w));
    }
    __syncthreads();

    const int w = tid >> 6;
    const int lane = tid & 63;
    const int lr = lane & 15;
    const int kg = lane >> 4;
    const int rowbase = (w >> 1) * 64;
    const int colbase = (w & 1) * 64;

    f32x4 acc[4][4];
    #pragma unroll
    for (int i = 0; i < 4; i++)
        #pragma unroll
        for (int j = 0; j < 4; j++) acc[i][j] = (f32x4){0.f, 0.f, 0.f, 0.f};

    #pragma unroll
    for (int kc = 0; kc < 4; kc++) {
        bf16x8 af[4], bfr[4];
        #pragma unroll
        for (int i = 0; i < 4; i++)
            af[i] = *(const bf16x8*)&As[kc][kg][rowbase + i * 16 + lr][0];
        #pragma unroll
        for (int j = 0; j < 4; j++)
            bfr[j] = *(const bf16x8*)&Bs[kc][kg][colbase + j * 16 + lr][0];
        #pragma unroll
        for (int i = 0; i < 4; i++)
            #pragma unroll
            for (int j = 0; j < 4; j++)
                acc[i][j] = __builtin_amdgcn_mfma_f32_16x16x32_bf16(af[i], bfr[j],
                                                                    acc[i][j], 0, 0, 0);
    }
    __syncthreads();   // all waves done reading As/Bs

    // write h (+b1, bf16) back into As; restage Bs rows 0..63 with W2
    #pragma unroll
    for (int i = 0; i < 4; i++) {
        #pragma unroll
        for (int reg = 0; reg < 4; reg++) {
            int row = rowbase + i * 16 + (lane >> 4) * 4 + reg;
            #pragma unroll
            for (int j = 0; j < 4; j++) {
                int col = colbase + j * 16 + lr;
                float v = acc[i][j][reg] + b1[col];
                float vn = __shfl_xor(v, 1, 64);
                if (!(lane & 1)) {
                    *(unsigned int*)&As[col >> 5][(col >> 3) & 3][row][col & 7] =
                        pack2bf(v, vn);
                }
            }
        }
    }
    #pragma unroll
    for (int i = 0; i < 8; i++) {
        int L = i * 256 + tid;          // 64 rows x 32 float4
        int r = L >> 5, kq = L & 31;
        float4 v = *(const float4*)&W2[(size_t)r * 128 + kq * 4];
        int k = kq * 4;
        *(uint2*)&Bs[k >> 5][(k >> 3) & 3][r][k & 7] =
            make_uint2(pack2bf(v.x, v.y), pack2bf(v.z, v.w));
    }
    __syncthreads();

    const int rowbase2 = w * 32;
    f32x4 acc2[2][4];
    #pragma unroll
    for (int i = 0; i < 2; i++)
        #pragma unroll
        for (int j = 0; j < 4; j++) acc2[i][j] = (f32x4){0.f, 0.f, 0.f, 0.f};

    #pragma unroll
    for (int kc = 0; kc < 4; kc++) {
        bf16x8 af2[2], bf2[4];
        #pragma unroll
        for (int i = 0; i < 2; i++)
            af2[i] = *(const bf16x8*)&As[kc][kg][rowbase2 + i * 16 + lr][0];
        #pragma unroll
        for (int j = 0; j < 4; j++)
            bf2[j] = *(const bf16x8*)&Bs[kc][kg][j * 16 + lr][0];
        #pragma unroll
        for (int i = 0; i < 2; i++)
            #pragma unroll
            for (int j = 0; j < 4; j++)
                acc2[i][j] = __builtin_amdgcn_mfma_f32_16x16x32_bf16(af2[i], bf2[j],
                                                                     acc2[i][j], 0, 0, 0);
    }

    #pragma unroll
    for (int i = 0; i < 2; i++) {
        #pragma unroll
        for (int reg = 0; reg < 4; reg++) {
            int row = rowbase2 + i * 16 + (lane >> 4) * 4 + reg;
            int gr = row0 + row;
            if (gr < nrows) {
                #pragma unroll
                for (int j = 0; j < 4; j++) {
                    int col = j * 16 + lr;
                    out[(size_t)gr * DOUT + col] = acc2[i][j][reg] + b2[col];
                }
            }
        }
    }
}

// ---------------- fused per-node softmax + aggregate (unchanged R10) ----------------

__global__ __launch_bounds__(256) void k_gat_node(const unsigned short* __restrict__ xl16,
                                                  const float* __restrict__ xr,
                                                  const float* __restrict__ att,
                                                  const float* __restrict__ bias,
                                                  const int* __restrict__ csr_off,
                                                  const int* __restrict__ prow,
                                                  const int* __restrict__ deg,
                                                  unsigned int* __restrict__ xout) {
    const int lane = threadIdx.x & 63;
    const int n = blockIdx.x * 4 + (threadIdx.x >> 6);
    if (n >= NN) return;

    const int l7 = lane & 7;
    const float2 xrv = *(const float2*)&xr[(size_t)n * DH + 2 * lane];
    const float2 attv = *(const float2*)&att[2 * lane];
    const int p0 = prow[n];
    const int dg = deg[n];
    const int pend = p0 + dg;
    const int pend_pad = p0 + ((dg + 7) & ~7);

    float ssum_l = 0.f;
    float ax = 0.f, ay = 0.f;

    const char* xlb = (const char*)xl16;
    const unsigned int lb = (unsigned int)lane * 4u;

    for (int p = p0; p < pend_pad; p += 8) {
        uint4 ia = *(const uint4*)&csr_off[p];
        uint4 ib = *(const uint4*)&csr_off[p + 4];
        unsigned int u0 = *(const unsigned int*)(xlb + (ia.x + lb));
        unsigned int u1 = *(const unsigned int*)(xlb + (ia.y + lb));
        unsigned int u2 = *(const unsigned int*)(xlb + (ia.z + lb));
        unsigned int u3 = *(const unsigned int*)(xlb + (ia.w + lb));
        unsigned int u4 = *(const unsigned int*)(xlb + (ib.x + lb));
        unsigned int u5 = *(const unsigned int*)(xlb + (ib.y + lb));
        unsigned int u6 = *(const unsigned int*)(xlb + (ib.z + lb));
        unsigned int u7 = *(const unsigned int*)(xlb + (ib.w + lb));
        unsigned int uu[8] = {u0, u1, u2, u3, u4, u5, u6, u7};

        float x0[8], x1[8], w[8];
        #pragma unroll
        for (int j = 0; j < 8; j++) {
            x0[j] = __uint_as_float(uu[j] << 16);
            x1[j] = __uint_as_float(uu[j] & 0xffff0000u);
            float z0 = x0[j] + xrv.x;
            float z1 = x1[j] + xrv.y;
            float l0 = fmaxf(z0, NEG * z0);
            float l1 = fmaxf(z1, NEG * z1);
            w[j] = fmaf(l0, attv.x, l1 * attv.y);
        }

        // merge tree
        float v4[4], v2[2], S;
        {
            const bool hi = (lane & 1);
            #pragma unroll
            for (int i = 0; i < 4; i++) {
                float keep = hi ? w[2 * i + 1] : w[2 * i];
                float send = hi ? w[2 * i] : w[2 * i + 1];
                v4[i] = keep + __shfl_xor(send, 1, 64);
            }
        }
        {
            const bool hi = (lane & 2);
            #pragma unroll
            for (int i = 0; i < 2; i++) {
                float keep = hi ? v4[2 * i + 1] : v4[2 * i];
                float send = hi ? v4[2 * i] : v4[2 * i + 1];
                v2[i] = keep + __shfl_xor(send, 2, 64);
            }
        }
        {
            const bool hi = (lane & 4);
            float keep = hi ? v2[1] : v2[0];
            float send = hi ? v2[0] : v2[1];
            S = keep + __shfl_xor(send, 4, 64);
        }
        S += __shfl_xor(S, 8, 64);
        S += __shfl_xor(S, 16, 64);
        S += __shfl_xor(S, 32, 64);

        float pe = (p + l7 < pend) ? __expf(S) : 0.f;
        ssum_l += pe;

        // unmerge tree: pe -> pe[0..7] on every lane
        float q = __shfl_xor(pe, 1, 64);
        float pA = (l7 & 1) ? q : pe;
        float pB = (l7 & 1) ? pe : q;
        float qA = __shfl_xor(pA, 2, 64);
        float qB = __shfl_xor(pB, 2, 64);
        float p00 = (l7 & 2) ? qA : pA;
        float p01 = (l7 & 2) ? qB : pB;
        float p10 = (l7 & 2) ? pA : qA;
        float p11 = (l7 & 2) ? pB : qB;
        float r00 = __shfl_xor(p00, 4, 64);
        float r01 = __shfl_xor(p01, 4, 64);
        float r10 = __shfl_xor(p10, 4, 64);
        float r11 = __shfl_xor(p11, 4, 64);
        float pe0 = (l7 & 4) ? r00 : p00;
        float pe1 = (l7 & 4) ? r01 : p01;
        float pe2 = (l7 & 4) ? r10 : p10;
        float pe3 = (l7 & 4) ? r11 : p11;
        float pe4 = (l7 & 4) ? p00 : r00;
        float pe5 = (l7 & 4) ? p01 : r01;
        float pe6 = (l7 & 4) ? p10 : r10;
        float pe7 = (l7 & 4) ? p11 : r11;

        ax = fmaf(pe0, x0[0], ax);  ay = fmaf(pe0, x1[0], ay);
        ax = fmaf(pe1, x0[1], ax);  ay = fmaf(pe1, x1[1], ay);
        ax = fmaf(pe2, x0[2], ax);  ay = fmaf(pe2, x1[2], ay);
        ax = fmaf(pe3, x0[3], ax);  ay = fmaf(pe3, x1[3], ay);
        ax = fmaf(pe4, x0[4], ax);  ay = fmaf(pe4, x1[4], ay);
        ax = fmaf(pe5, x0[5], ax);  ay = fmaf(pe5, x1[5], ay);
        ax = fmaf(pe6, x0[6], ax);  ay = fmaf(pe6, x1[6], ay);
        ax = fmaf(pe7, x0[7], ax);  ay = fmaf(pe7, x1[7], ay);
    }

    float st = ssum_l;
    st += __shfl_xor(st, 1, 64);
    st += __shfl_xor(st, 2, 64);
    st += __shfl_xor(st, 4, 64);
    const float inv = (st > 0.f) ? 1.f / st : 0.f;

    const float2 bv = *(const float2*)&bias[2 * lane];
    const float o0 = fmaxf(fmaf(ax, inv, bv.x), 0.f);
    const float o1 = fmaxf(fmaf(ay, inv, bv.y), 0.f);
    xout[(size_t)n * (DH / 2) + lane] = pack2bf(o0, o1);
}

// ---------------- host launch ----------------

static inline size_t align256(size_t x) { return (x + 255) & ~(size_t)255; }

extern "C" void kernel_launch(void* const* d_in, const int* in_sizes, int n_in,
                              void* d_out, int out_size, void* d_ws, size_t ws_size,
                              hipStream_t stream) {
    (void)in_sizes; (void)n_in; (void)out_size; (void)ws_size;

    const float* x   = (const float*)d_in[0];
    const int* ei    = (const int*)d_in[1];
    const float* Wl  = (const float*)d_in[2];
    const float* bl  = (const float*)d_in[3];
    const float* Wr  = (const float*)d_in[4];
    const float* br  = (const float*)d_in[5];
    const float* att = (const float*)d_in[6];
    const float* bias= (const float*)d_in[7];
    const float* W1  = (const float*)d_in[8];
    const float* b1  = (const float*)d_in[9];
    const float* W2  = (const float*)d_in[10];
    const float* b2  = (const float*)d_in[11];
    float* out = (float*)d_out;

    const int* src = ei;
    const int* dst = ei + EE;

    char* w = (char*)d_ws;
    unsigned int* xA = (unsigned int*)w; w += align256((size_t)NN * (DH / 2) * 4);
    unsigned int* xB = (unsigned int*)w; w += align256((size_t)NN * (DH / 2) * 4);
    unsigned int* xl16 = (unsigned int*)w; w += align256((size_t)NN * DH * 2);
    float* xrb = (float*)w; w += align256((size_t)NN * DH * 4);
    unsigned int* pairs = (unsigned int*)w; w += align256((size_t)NBK * BCAP * 4);
    int* csr_off = (int*)w; w += align256((size_t)NBK * CCAP * 4);
    int* prow    = (int*)w; w += align256((size_t)NN * 4);
    int* deg     = (int*)w; w += align256((size_t)NN * 4);
    int* bucket_cursor = (int*)w; w += align256(NBK * 4);

    const int nb_chunk = (EE + CHUNK - 1) / CHUNK;  // 391
    const int nb_bkt  = (NN + 255) / 256;           // 196
    const int nb_gemm = (NN + 127) / 128;           // 391
    const int nb_node = (NN + 3) / 4;               // 12500

    // ---- build bucketed CSR (single-pass, fixed-capacity regions) ----
    hipMemsetAsync(bucket_cursor, 0, NBK * 4, stream);
    k_scatter<<<nb_chunk, 256, 0, stream>>>(src, dst, bucket_cursor, pairs);
    k_bucket<<<nb_bkt, 256, 0, stream>>>(pairs, bucket_cursor, csr_off, prow, deg);

    // ---- 3 GATv2 layers ----
    const void* xin = (const void*)x;   // layer 0: fp32
    for (int l = 0; l < 3; ++l) {
        const float* Wl_l = Wl + (size_t)l * DH * DH;
        const float* Wr_l = Wr + (size_t)l * DH * DH;
        const float* bl_l = bl + (size_t)l * DH;
        const float* br_l = br + (size_t)l * DH;
        const float* att_l = att + (size_t)l * DH;
        const float* bias_l = bias + (size_t)l * DH;
        unsigned int* xo = (l & 1) ? xB : xA;

        if (l == 0)
            k_dual<false><<<nb_gemm, 256, 0, stream>>>(xin, Wl_l, bl_l, xl16,
                                                       Wr_l, br_l, xrb, NN);
        else
            k_dual<true><<<nb_gemm, 256, 0, stream>>>(xin, Wl_l, bl_l, xl16,
                                                      Wr_l, br_l, xrb, NN);
        k_gat_node<<<nb_node, 256, 0, stream>>>((const unsigned short*)xl16, xrb,
                                                att_l, bias_l, csr_off, prow, deg, xo);
        xin = (const void*)xo;
    }

    // ---- fused head MLP ----
    k_head<<<nb_gemm, 256, 0, stream>>>(xin, W1, b1, W2, b2, out, NN);
}

// Round 13
// 331.267 us; speedup vs baseline: 1.1545x; 1.1545x over previous
//
#include <hip/hip_runtime.h>
#include <hip/hip_bf16.h>

#define NN 50000
#define EE 1600000
#define DH 128
#define DOUT 64
#define NEG 0.2f
#define NBK 256            // bucket array size (used: (NN+255)>>8 = 196)
#define CHUNK 4096         // edges per scatter block
#define BCAP 10240         // per-bucket pair capacity (lambda=8192, +22 sigma)
#define CCAP 12288         // per-bucket csr capacity (BCAP + 256*8 pad slack)

typedef short bf16x8 __attribute__((ext_vector_type(8)));
typedef float f32x4 __attribute__((ext_vector_type(4)));
typedef float f32x2 __attribute__((ext_vector_type(2)));

// ---------------- CSR build (single-pass bucketed) ----------------

__global__ __launch_bounds__(256) void k_scatter(const int* __restrict__ src,
                                                 const int* __restrict__ dst,
                                                 int* __restrict__ bucket_cursor,
                                                 unsigned int* __restrict__ pairs) {
    __shared__ int lh[NBK];
    __shared__ int lbase[NBK];
    lh[threadIdx.x] = 0;
    __syncthreads();
    const int e0 = blockIdx.x * CHUNK;
    int dl[CHUNK / 256];
    #pragma unroll
    for (int k = 0; k < CHUNK / 256; k++) {
        int e = e0 + k * 256 + threadIdx.x;
        dl[k] = (e < EE) ? dst[e] : -1;
        if (dl[k] >= 0) atomicAdd(&lh[((unsigned)dl[k]) >> 8], 1);
    }
    __syncthreads();
    int c = lh[threadIdx.x];
    lbase[threadIdx.x] = c ? (threadIdx.x * BCAP +
                              atomicAdd(&bucket_cursor[threadIdx.x], c)) : 0;
    __syncthreads();
    lh[threadIdx.x] = 0;   // reuse as local running cursor
    __syncthreads();
    #pragma unroll
    for (int k = 0; k < CHUNK / 256; k++) {
        int e = e0 + k * 256 + threadIdx.x;
        if (dl[k] >= 0) {
            int b = ((unsigned)dl[k]) >> 8;
            int loc = atomicAdd(&lh[b], 1);
            pairs[lbase[b] + loc] =
                (unsigned)src[e] | (((unsigned)dl[k] & 255u) << 16);
        }
    }
}

__global__ __launch_bounds__(256) void k_bucket(const unsigned int* __restrict__ pairs,
                                                const int* __restrict__ bucket_cursor,
                                                int* __restrict__ csr_off,
                                                int* __restrict__ prow,
                                                int* __restrict__ deg) {
    __shared__ int cnt[256];
    __shared__ int sbase[256];
    __shared__ int scn[256];
    __shared__ int cur[256];
    const int b = blockIdx.x;
    const int t = threadIdx.x;
    const int pstart = b * BCAP;
    const int pcnt = bucket_cursor[b];

    cnt[t] = 0;
    cur[t] = 0;
    __syncthreads();
    for (int i = t; i < pcnt; i += 256)
        atomicAdd(&cnt[pairs[pstart + i] >> 16], 1);
    __syncthreads();

    const int d = cnt[t];
    const int padded = (d + 7) & ~7;
    scn[t] = padded;
    __syncthreads();
    #pragma unroll
    for (int off = 1; off < 256; off <<= 1) {
        int v = (t >= off) ? scn[t - off] : 0;
        __syncthreads();
        scn[t] += v;
        __syncthreads();
    }
    const int mybase = scn[t] - padded;   // exclusive scan (bucket-relative)
    sbase[t] = mybase;
    const int cb = b * CCAP;              // csr region base for this bucket
    const int node = b * 256 + t;
    if (node < NN) {
        prow[node] = cb + mybase;
        deg[node] = d;
    }
    __syncthreads();

    for (int i = t; i < pcnt; i += 256) {
        unsigned int pr = pairs[pstart + i];
        int ln = (int)(pr >> 16);
        int pos = atomicAdd(&cur[ln], 1);
        csr_off[cb + sbase[ln] + pos] = (int)((pr & 0xffffu) << 8);
    }
    __syncthreads();

    for (int p = d; p < padded; p++) csr_off[cb + mybase + p] = 0;
}

// ---------------- helpers ----------------

static __device__ __forceinline__ unsigned int f2bf(float f) {
    unsigned int u = __float_as_uint(f);
    return (u + 0x7fffu + ((u >> 16) & 1u)) >> 16;  // RNE
}
static __device__ __forceinline__ unsigned int pack2bf(float lo, float hi) {
    return f2bf(lo) | (f2bf(hi) << 16);
}

// ---------------- merged dual MFMA GEMM (64KB LDS: Wr restaged) ----------------
// stage A once + Wl; pass1 -> xl16 (bf16); restage Wr into same B buffer;
// pass2 -> xrb (fp32). 2 blocks/CU.

template <bool ABF>
__global__ __launch_bounds__(256) void k_dual(const void* __restrict__ X,
                                              const float* __restrict__ Wl,
                                              const float* __restrict__ bl,
                                              unsigned int* __restrict__ Cl,
                                              const float* __restrict__ Wr,
                                              const float* __restrict__ br,
                                              float* __restrict__ Cr,
                                              int nrows) {
    __shared__ __align__(16) unsigned short As[4][4][128][8];
    __shared__ __align__(16) unsigned short Bs[4][4][128][8];

    const int tid = threadIdx.x;
    const int row0 = blockIdx.x * 128;

    // stage A
    if constexpr (ABF) {
        const uint4* X4 = (const uint4*)X;
        #pragma unroll
        for (int i = 0; i < 8; i++) {
            int L = i * 256 + tid;          // 2048 uint4 (128 rows x 16)
            int r = L >> 4, q = L & 15;
            int gr = row0 + r;
            uint4 v = make_uint4(0u, 0u, 0u, 0u);
            if (gr < nrows) v = X4[(size_t)gr * 16 + q];
            *(uint4*)&As[q >> 2][q & 3][r][0] = v;
        }
    } else {
        const float* Xf = (const float*)X;
        #pragma unroll
        for (int i = 0; i < 16; i++) {
            int L = i * 256 + tid;          // 4096 float4
            int r = L >> 5, kq = L & 31;
            int gr = row0 + r;
            float4 v = make_float4(0.f, 0.f, 0.f, 0.f);
            if (gr < nrows) v = *(const float4*)&Xf[(size_t)gr * 128 + kq * 4];
            int k = kq * 4;
            *(uint2*)&As[k >> 5][(k >> 3) & 3][r][k & 7] =
                make_uint2(pack2bf(v.x, v.y), pack2bf(v.z, v.w));
        }
    }
    // stage Bs <- Wl
    #pragma unroll
    for (int i = 0; i < 16; i++) {
        int L = i * 256 + tid;
        int r = L >> 5, kq = L & 31;
        int k = kq * 4;
        float4 v = *(const float4*)&Wl[(size_t)r * 128 + kq * 4];
        *(uint2*)&Bs[k >> 5][(k >> 3) & 3][r][k & 7] =
            make_uint2(pack2bf(v.x, v.y), pack2bf(v.z, v.w));
    }
    __syncthreads();

    const int w = tid >> 6;
    const int lane = tid & 63;
    const int lr = lane & 15;
    const int kg = lane >> 4;
    const int rowbase = (w >> 1) * 64;
    const int colbase = (w & 1) * 64;

    f32x4 acc[4][4];

    // ---- pass 1: Wl ----
    #pragma unroll
    for (int i = 0; i < 4; i++)
        #pragma unroll
        for (int j = 0; j < 4; j++) acc[i][j] = (f32x4){0.f, 0.f, 0.f, 0.f};
    #pragma unroll
    for (int kc = 0; kc < 4; kc++) {
        bf16x8 af[4], bfr[4];
        #pragma unroll
        for (int i = 0; i < 4; i++)
            af[i] = *(const bf16x8*)&As[kc][kg][rowbase + i * 16 + lr][0];
        #pragma unroll
        for (int j = 0; j < 4; j++)
            bfr[j] = *(const bf16x8*)&Bs[kc][kg][colbase + j * 16 + lr][0];
        #pragma unroll
        for (int i = 0; i < 4; i++)
            #pragma unroll
            for (int j = 0; j < 4; j++)
                acc[i][j] = __builtin_amdgcn_mfma_f32_16x16x32_bf16(af[i], bfr[j],
                                                                    acc[i][j], 0, 0, 0);
    }
    __syncthreads();   // all waves done reading Bs

    // restage Bs <- Wr (overlaps with epilogue-1 stores)
    #pragma unroll
    for (int i = 0; i < 16; i++) {
        int L = i * 256 + tid;
        int r = L >> 5, kq = L & 31;
        int k = kq * 4;
        float4 u = *(const float4*)&Wr[(size_t)r * 128 + kq * 4];
        *(uint2*)&Bs[k >> 5][(k >> 3) & 3][r][k & 7] =
            make_uint2(pack2bf(u.x, u.y), pack2bf(u.z, u.w));
    }
    // epilogue 1 -> packed bf16
    #pragma unroll
    for (int i = 0; i < 4; i++) {
        #pragma unroll
        for (int reg = 0; reg < 4; reg++) {
            int row = rowbase + i * 16 + (lane >> 4) * 4 + reg;
            int gr = row0 + row;
            if (gr < nrows) {
                #pragma unroll
                for (int j = 0; j < 4; j++) {
                    int col = colbase + j * 16 + lr;
                    float v = acc[i][j][reg] + bl[col];
                    float vn = __shfl_xor(v, 1, 64);
                    if (!(lane & 1))
                        Cl[(size_t)gr * (DH / 2) + (col >> 1)] = pack2bf(v, vn);
                }
            }
        }
    }
    __syncthreads();

    // ---- pass 2: Wr ----
    #pragma unroll
    for (int i = 0; i < 4; i++)
        #pragma unroll
        for (int j = 0; j < 4; j++) acc[i][j] = (f32x4){0.f, 0.f, 0.f, 0.f};
    #pragma unroll
    for (int kc = 0; kc < 4; kc++) {
        bf16x8 af[4], bfr[4];
        #pragma unroll
        for (int i = 0; i < 4; i++)
            af[i] = *(const bf16x8*)&As[kc][kg][rowbase + i * 16 + lr][0];
        #pragma unroll
        for (int j = 0; j < 4; j++)
            bfr[j] = *(const bf16x8*)&Bs[kc][kg][colbase + j * 16 + lr][0];
        #pragma unroll
        for (int i = 0; i < 4; i++)
            #pragma unroll
            for (int j = 0; j < 4; j++)
                acc[i][j] = __builtin_amdgcn_mfma_f32_16x16x32_bf16(af[i], bfr[j],
                                                                    acc[i][j], 0, 0, 0);
    }
    #pragma unroll
    for (int i = 0; i < 4; i++) {
        #pragma unroll
        for (int reg = 0; reg < 4; reg++) {
            int row = rowbase + i * 16 + (lane >> 4) * 4 + reg;
            int gr = row0 + row;
            if (gr < nrows) {
                #pragma unroll
                for (int j = 0; j < 4; j++) {
                    int col = colbase + j * 16 + lr;
                    Cr[(size_t)gr * DH + col] = acc[i][j][reg] + br[col];
                }
            }
        }
    }
}

// ---------------- fused head: out = (X@W1.T + b1)@W2.T + b2 ----------------

__global__ __launch_bounds__(256) void k_head(const void* __restrict__ Xbf,
                                              const float* __restrict__ W1,
                                              const float* __restrict__ b1,
                                              const float* __restrict__ W2,
                                              const float* __restrict__ b2,
                                              float* __restrict__ out,
                                              int nrows) {
    __shared__ __align__(16) unsigned short As[4][4][128][8];
    __shared__ __align__(16) unsigned short Bs[4][4][128][8];

    const int tid = threadIdx.x;
    const int row0 = blockIdx.x * 128;

    const uint4* X4 = (const uint4*)Xbf;
    #pragma unroll
    for (int i = 0; i < 8; i++) {
        int L = i * 256 + tid;
        int r = L >> 4, q = L & 15;
        int gr = row0 + r;
        uint4 v = make_uint4(0u, 0u, 0u, 0u);
        if (gr < nrows) v = X4[(size_t)gr * 16 + q];
        *(uint4*)&As[q >> 2][q & 3][r][0] = v;
    }
    #pragma unroll
    for (int i = 0; i < 16; i++) {
        int L = i * 256 + tid;
        int r = L >> 5, kq = L & 31;
        float4 v = *(const float4*)&W1[(size_t)r * 128 + kq * 4];
        int k = kq * 4;
        *(uint2*)&Bs[k >> 5][(k >> 3) & 3][r][k & 7] =
            make_uint2(pack2bf(v.x, v.y), pack2bf(v.z, v.w));
    }
    __syncthreads();

    const int w = tid >> 6;
    const int lane = tid & 63;
    const int lr = lane & 15;
    const int kg = lane >> 4;
    const int rowbase = (w >> 1) * 64;
    const int colbase = (w & 1) * 64;

    f32x4 acc[4][4];
    #pragma unroll
    for (int i = 0; i < 4; i++)
        #pragma unroll
        for (int j = 0; j < 4; j++) acc[i][j] = (f32x4){0.f, 0.f, 0.f, 0.f};

    #pragma unroll
    for (int kc = 0; kc < 4; kc++) {
        bf16x8 af[4], bfr[4];
        #pragma unroll
        for (int i = 0; i < 4; i++)
            af[i] = *(const bf16x8*)&As[kc][kg][rowbase + i * 16 + lr][0];
        #pragma unroll
        for (int j = 0; j < 4; j++)
            bfr[j] = *(const bf16x8*)&Bs[kc][kg][colbase + j * 16 + lr][0];
        #pragma unroll
        for (int i = 0; i < 4; i++)
            #pragma unroll
            for (int j = 0; j < 4; j++)
                acc[i][j] = __builtin_amdgcn_mfma_f32_16x16x32_bf16(af[i], bfr[j],
                                                                    acc[i][j], 0, 0, 0);
    }
    __syncthreads();   // all waves done reading As/Bs

    // write h (+b1, bf16) back into As; restage Bs rows 0..63 with W2
    #pragma unroll
    for (int i = 0; i < 4; i++) {
        #pragma unroll
        for (int reg = 0; reg < 4; reg++) {
            int row = rowbase + i * 16 + (lane >> 4) * 4 + reg;
            #pragma unroll
            for (int j = 0; j < 4; j++) {
                int col = colbase + j * 16 + lr;
                float v = acc[i][j][reg] + b1[col];
                float vn = __shfl_xor(v, 1, 64);
                if (!(lane & 1)) {
                    *(unsigned int*)&As[col >> 5][(col >> 3) & 3][row][col & 7] =
                        pack2bf(v, vn);
                }
            }
        }
    }
    #pragma unroll
    for (int i = 0; i < 8; i++) {
        int L = i * 256 + tid;          // 64 rows x 32 float4
        int r = L >> 5, kq = L & 31;
        float4 v = *(const float4*)&W2[(size_t)r * 128 + kq * 4];
        int k = kq * 4;
        *(uint2*)&Bs[k >> 5][(k >> 3) & 3][r][k & 7] =
            make_uint2(pack2bf(v.x, v.y), pack2bf(v.z, v.w));
    }
    __syncthreads();

    const int rowbase2 = w * 32;
    f32x4 acc2[2][4];
    #pragma unroll
    for (int i = 0; i < 2; i++)
        #pragma unroll
        for (int j = 0; j < 4; j++) acc2[i][j] = (f32x4){0.f, 0.f, 0.f, 0.f};

    #pragma unroll
    for (int kc = 0; kc < 4; kc++) {
        bf16x8 af2[2], bf2[4];
        #pragma unroll
        for (int i = 0; i < 2; i++)
            af2[i] = *(const bf16x8*)&As[kc][kg][rowbase2 + i * 16 + lr][0];
        #pragma unroll
        for (int j = 0; j < 4; j++)
            bf2[j] = *(const bf16x8*)&Bs[kc][kg][j * 16 + lr][0];
        #pragma unroll
        for (int i = 0; i < 2; i++)
            #pragma unroll
            for (int j = 0; j < 4; j++)
                acc2[i][j] = __builtin_amdgcn_mfma_f32_16x16x32_bf16(af2[i], bf2[j],
                                                                     acc2[i][j], 0, 0, 0);
    }

    #pragma unroll
    for (int i = 0; i < 2; i++) {
        #pragma unroll
        for (int reg = 0; reg < 4; reg++) {
            int row = rowbase2 + i * 16 + (lane >> 4) * 4 + reg;
            int gr = row0 + row;
            if (gr < nrows) {
                #pragma unroll
                for (int j = 0; j < 4; j++) {
                    int col = j * 16 + lr;
                    out[(size_t)gr * DOUT + col] = acc2[i][j][reg] + b2[col];
                }
            }
        }
    }
}

// ---------------- fused per-node softmax + aggregate ----------------
// R11 structure; edge math on f32x2 (v_pk_* on gfx950), pe broadcast via
// ds_swizzle BitMode with LITERAL offsets (src = (lane & 0x18) | j):
// offset = (xor=0)<<10 | (or=j)<<5 | (and=0x18).

__global__ __launch_bounds__(256) void k_gat_node(const unsigned short* __restrict__ xl16,
                                                  const float* __restrict__ xr,
                                                  const float* __restrict__ att,
                                                  const float* __restrict__ bias,
                                                  const int* __restrict__ csr_off,
                                                  const int* __restrict__ prow,
                                                  const int* __restrict__ deg,
                                                  unsigned int* __restrict__ xout) {
    const int lane = threadIdx.x & 63;
    const int n = blockIdx.x * 4 + (threadIdx.x >> 6);
    if (n >= NN) return;

    const int l7 = lane & 7;
    const f32x2 xrp = *(const f32x2*)&xr[(size_t)n * DH + 2 * lane];
    const f32x2 attp = *(const f32x2*)&att[2 * lane];
    const int p0 = prow[n];
    const int dg = deg[n];
    const int pend = p0 + dg;
    const int pend_pad = p0 + ((dg + 7) & ~7);

    float ssum_l = 0.f;
    f32x2 axy = {0.f, 0.f};

    const char* xlb = (const char*)xl16;
    const unsigned int lb = (unsigned int)lane * 4u;

    for (int p = p0; p < pend_pad; p += 8) {
        uint4 ia = *(const uint4*)&csr_off[p];
        uint4 ib = *(const uint4*)&csr_off[p + 4];
        unsigned int u0 = *(const unsigned int*)(xlb + (ia.x + lb));
        unsigned int u1 = *(const unsigned int*)(xlb + (ia.y + lb));
        unsigned int u2 = *(const unsigned int*)(xlb + (ia.z + lb));
        unsigned int u3 = *(const unsigned int*)(xlb + (ia.w + lb));
        unsigned int u4 = *(const unsigned int*)(xlb + (ib.x + lb));
        unsigned int u5 = *(const unsigned int*)(xlb + (ib.y + lb));
        unsigned int u6 = *(const unsigned int*)(xlb + (ib.z + lb));
        unsigned int u7 = *(const unsigned int*)(xlb + (ib.w + lb));
        unsigned int uu[8] = {u0, u1, u2, u3, u4, u5, u6, u7};

        f32x2 xq[8];
        float w[8];
        #pragma unroll
        for (int j = 0; j < 8; j++) {
            f32x2 xp;
            xp.x = __uint_as_float(uu[j] << 16);
            xp.y = __uint_as_float(uu[j] & 0xffff0000u);
            xq[j] = xp;
            f32x2 zp = xp + xrp;                      // v_pk_add_f32
            f32x2 lp = __builtin_elementwise_max(zp, zp * NEG);  // pk_mul + pk_max
            f32x2 wp = lp * attp;                     // v_pk_mul_f32
            w[j] = wp.x + wp.y;
        }

        // merge tree: lane ends with w[l7] summed over its 8-lane dim group
        float v4[4], v2[2], S;
        {
            const bool hi = (lane & 1);
            #pragma unroll
            for (int i = 0; i < 4; i++) {
                float keep = hi ? w[2 * i + 1] : w[2 * i];
                float send = hi ? w[2 * i] : w[2 * i + 1];
                v4[i] = keep + __shfl_xor(send, 1, 64);
            }
        }
        {
            const bool hi = (lane & 2);
            #pragma unroll
            for (int i = 0; i < 2; i++) {
                float keep = hi ? v4[2 * i + 1] : v4[2 * i];
                float send = hi ? v4[2 * i] : v4[2 * i + 1];
                v2[i] = keep + __shfl_xor(send, 2, 64);
            }
        }
        {
            const bool hi = (lane & 4);
            float keep = hi ? v2[1] : v2[0];
            float send = hi ? v2[0] : v2[1];
            S = keep + __shfl_xor(send, 4, 64);
        }
        S += __shfl_xor(S, 8, 64);
        S += __shfl_xor(S, 16, 64);
        S += __shfl_xor(S, 32, 64);

        float pe = (p + l7 < pend) ? __expf(S) : 0.f;
        ssum_l += pe;

        // broadcast pe_j to all lanes: ds_swizzle BitMode, literal offsets
        // offset = (or=j)<<5 | (and=0x18); src = (lane & 0x18) | j
        const int pei = __float_as_int(pe);
        #define BCAST(J, OFF) \
            { float pj = __int_as_float(__builtin_amdgcn_ds_swizzle(pei, OFF)); \
              axy += xq[J] * pj; }
        BCAST(0, 0x018)
        BCAST(1, 0x038)
        BCAST(2, 0x058)
        BCAST(3, 0x078)
        BCAST(4, 0x098)
        BCAST(5, 0x0B8)
        BCAST(6, 0x0D8)
        BCAST(7, 0x0F8)
        #undef BCAST
    }

    float st = ssum_l;
    st += __shfl_xor(st, 1, 64);
    st += __shfl_xor(st, 2, 64);
    st += __shfl_xor(st, 4, 64);
    const float inv = (st > 0.f) ? 1.f / st : 0.f;

    const f32x2 bvp = *(const f32x2*)&bias[2 * lane];
    f32x2 o = axy * inv + bvp;
    o = __builtin_elementwise_max(o, (f32x2){0.f, 0.f});
    xout[(size_t)n * (DH / 2) + lane] = pack2bf(o.x, o.y);
}

// ---------------- host launch ----------------

static inline size_t align256(size_t x) { return (x + 255) & ~(size_t)255; }

extern "C" void kernel_launch(void* const* d_in, const int* in_sizes, int n_in,
                              void* d_out, int out_size, void* d_ws, size_t ws_size,
                              hipStream_t stream) {
    (void)in_sizes; (void)n_in; (void)out_size; (void)ws_size;

    const float* x   = (const float*)d_in[0];
    const int* ei    = (const int*)d_in[1];
    const float* Wl  = (const float*)d_in[2];
    const float* bl  = (const float*)d_in[3];
    const float* Wr  = (const float*)d_in[4];
    const float* br  = (const float*)d_in[5];
    const float* att = (const float*)d_in[6];
    const float* bias= (const float*)d_in[7];
    const float* W1  = (const float*)d_in[8];
    const float* b1  = (const float*)d_in[9];
    const float* W2  = (const float*)d_in[10];
    const float* b2  = (const float*)d_in[11];
    float* out = (float*)d_out;

    const int* src = ei;
    const int* dst = ei + EE;

    char* w = (char*)d_ws;
    unsigned int* xA = (unsigned int*)w; w += align256((size_t)NN * (DH / 2) * 4);
    unsigned int* xB = (unsigned int*)w; w += align256((size_t)NN * (DH / 2) * 4);
    unsigned int* xl16 = (unsigned int*)w; w += align256((size_t)NN * DH * 2);
    float* xrb = (float*)w; w += align256((size_t)NN * DH * 4);
    unsigned int* pairs = (unsigned int*)w; w += align256((size_t)NBK * BCAP * 4);
    int* csr_off = (int*)w; w += align256((size_t)NBK * CCAP * 4);
    int* prow    = (int*)w; w += align256((size_t)NN * 4);
    int* deg     = (int*)w; w += align256((size_t)NN * 4);
    int* bucket_cursor = (int*)w; w += align256(NBK * 4);

    const int nb_chunk = (EE + CHUNK - 1) / CHUNK;  // 391
    const int nb_bkt  = (NN + 255) / 256;           // 196
    const int nb_gemm = (NN + 127) / 128;           // 391
    const int nb_node = (NN + 3) / 4;               // 12500

    // ---- build bucketed CSR (single-pass, fixed-capacity regions) ----
    hipMemsetAsync(bucket_cursor, 0, NBK * 4, stream);
    k_scatter<<<nb_chunk, 256, 0, stream>>>(src, dst, bucket_cursor, pairs);
    k_bucket<<<nb_bkt, 256, 0, stream>>>(pairs, bucket_cursor, csr_off, prow, deg);

    // ---- 3 GATv2 layers ----
    const void* xin = (const void*)x;   // layer 0: fp32
    for (int l = 0; l < 3; ++l) {
        const float* Wl_l = Wl + (size_t)l * DH * DH;
        const float* Wr_l = Wr + (size_t)l * DH * DH;
        const float* bl_l = bl + (size_t)l * DH;
        const float* br_l = br + (size_t)l * DH;
        const float* att_l = att + (size_t)l * DH;
        const float* bias_l = bias + (size_t)l * DH;
        unsigned int* xo = (l & 1) ? xB : xA;

        if (l == 0)
            k_dual<false><<<nb_gemm, 256, 0, stream>>>(xin, Wl_l, bl_l, xl16,
                                                       Wr_l, br_l, xrb, NN);
        else
            k_dual<true><<<nb_gemm, 256, 0, stream>>>(xin, Wl_l, bl_l, xl16,
                                                      Wr_l, br_l, xrb, NN);
        k_gat_node<<<nb_node, 256, 0, stream>>>((const unsigned short*)xl16, xrb,
                                                att_l, bias_l, csr_off, prow, deg, xo);
        xin = (const void*)xo;
    }

    // ---- fused head MLP ----
    k_head<<<nb_gemm, 256, 0, stream>>>(xin, W1, b1, W2, b2, out, NN);
}